// Round 3
// baseline (50.301 us; speedup 1.0000x reference)
//
#include <hip/hip_runtime.h>
#include <float.h>
#include <math.h>

namespace {

constexpr int kB  = 16;
constexpr int kC  = 64;
constexpr int kH  = 224;
constexpr int kW  = 224;
constexpr int kOH = 112;
constexpr int kOW = 112;
constexpr int kOW4 = kOW / 4;                       // 28 output-quads per row
constexpr int kTotalThreads = kB * kC * kOH * kOW4; // 3,211,264

typedef float f32x4 __attribute__((ext_vector_type(4)));

__device__ __forceinline__ float fast_rcp(float x) {
  return __builtin_amdgcn_rcpf(x);
}

// One 2x2 window: taps a,b (row0), c,d (row1), blend weight beta.
__device__ __forceinline__ float window(float a, float b, float c, float d,
                                        float beta) {
  // --- EDSCW ---
  float avg  = (a + b + c + d) * 0.25f;
  float avg2 = avg * avg;
  float ta   = 2.0f * avg;
  float da = (ta * a) * fast_rcp(fmaf(a, a, avg2));
  float db = (ta * b) * fast_rcp(fmaf(b, b, avg2));
  float dc = (ta * c) * fast_rcp(fmaf(c, c, avg2));
  float dd = (ta * d) * fast_rcp(fmaf(d, d, avg2));
  float md = fmaxf(fmaxf(da, db), fmaxf(dc, dd));
  float ea = __expf(da - md);
  float eb = __expf(db - md);
  float ec = __expf(dc - md);
  float ed = __expf(dd - md);
  float edscw = (ea * a + eb * b + ec * c + ed * d) *
                fast_rcp(ea + eb + ec + ed);
  // --- EM (SoftPool) ---
  float mx = fmaxf(fmaxf(a, b), fmaxf(c, d));
  float fa = __expf(a - mx);
  float fb = __expf(b - mx);
  float fc = __expf(c - mx);
  float fd = __expf(d - mx);
  float em = (fa * a + fb * b + fc * c + fd * d) *
             fast_rcp(fa + fb + fc + fd);
  // --- blend + nan_to_num ---
  float r = beta * edscw + (1.0f - beta) * em;
  if (isnan(r))      r = 0.0f;
  else if (isinf(r)) r = (r > 0.0f) ? FLT_MAX : -FLT_MAX;
  return r;
}

__global__ void __launch_bounds__(256)
adapool2d_kernel(const float* __restrict__ x,
                 const float* __restrict__ beta,
                 float* __restrict__ out) {
  int tid = blockIdx.x * blockDim.x + threadIdx.x;
  if (tid >= kTotalThreads) return;

  int ow4 = tid % kOW4;          // which quad of output columns
  int t   = tid / kOW4;
  int oh  = t % kOH;
  int bc  = t / kOH;             // fused batch*channel

  // Input window rows 2*oh, 2*oh+1; columns 8*ow4 .. 8*ow4+7
  const float* rowp = x + (size_t)bc * (kH * kW)
                        + (size_t)(2 * oh) * kW
                        + 8 * ow4;
  f32x4 a0 = __builtin_nontemporal_load(reinterpret_cast<const f32x4*>(rowp));
  f32x4 a1 = __builtin_nontemporal_load(reinterpret_cast<const f32x4*>(rowp + 4));
  f32x4 b0 = __builtin_nontemporal_load(reinterpret_cast<const f32x4*>(rowp + kW));
  f32x4 b1 = __builtin_nontemporal_load(reinterpret_cast<const f32x4*>(rowp + kW + 4));

  // beta[oh][4*ow4 .. 4*ow4+3] — 16B aligned; cached (heavily reused over B*C)
  f32x4 bt = *reinterpret_cast<const f32x4*>(beta + oh * kOW + 4 * ow4);

  f32x4 o;
  o.x = window(a0.x, a0.y, b0.x, b0.y, bt.x);
  o.y = window(a0.z, a0.w, b0.z, b0.w, bt.y);
  o.z = window(a1.x, a1.y, b1.x, b1.y, bt.z);
  o.w = window(a1.z, a1.w, b1.z, b1.w, bt.w);

  float* outp = out + (size_t)bc * (kOH * kOW) + (size_t)oh * kOW + 4 * ow4;
  __builtin_nontemporal_store(o, reinterpret_cast<f32x4*>(outp));
}

}  // namespace

extern "C" void kernel_launch(void* const* d_in, const int* in_sizes, int n_in,
                              void* d_out, int out_size, void* d_ws, size_t ws_size,
                              hipStream_t stream) {
  const float* x    = (const float*)d_in[0];
  const float* beta = (const float*)d_in[1];
  float* out        = (float*)d_out;

  constexpr int threads = 256;
  constexpr int blocks  = (kTotalThreads + threads - 1) / threads;
  adapool2d_kernel<<<blocks, threads, 0, stream>>>(x, beta, out);
}

// Round 4
// 43.005 us; speedup vs baseline: 1.1697x; 1.1697x over previous
//
#include <hip/hip_runtime.h>
#include <float.h>
#include <math.h>

namespace {

constexpr int kB  = 16;
constexpr int kC  = 64;
constexpr int kH  = 224;
constexpr int kW  = 224;
constexpr int kOH = 112;
constexpr int kOW = 112;
constexpr int kOW2 = kOW / 2;                       // 56 output-pairs per row
constexpr int kTotalThreads = kB * kC * kOH * kOW2; // 6,422,528

typedef float f32x2 __attribute__((ext_vector_type(2)));

__device__ __forceinline__ float fast_rcp(float x) {
  return __builtin_amdgcn_rcpf(x);
}

// One 2x2 window: taps a,b (row0), c,d (row1), blend weight beta.
__device__ __forceinline__ float window(float a, float b, float c, float d,
                                        float beta) {
  // --- EDSCW ---
  float avg  = (a + b + c + d) * 0.25f;
  float avg2 = avg * avg;
  float ta   = 2.0f * avg;
  float da = (ta * a) * fast_rcp(fmaf(a, a, avg2));
  float db = (ta * b) * fast_rcp(fmaf(b, b, avg2));
  float dc = (ta * c) * fast_rcp(fmaf(c, c, avg2));
  float dd = (ta * d) * fast_rcp(fmaf(d, d, avg2));
  float md = fmaxf(fmaxf(da, db), fmaxf(dc, dd));
  float ea = __expf(da - md);
  float eb = __expf(db - md);
  float ec = __expf(dc - md);
  float ed = __expf(dd - md);
  float edscw = (ea * a + eb * b + ec * c + ed * d) *
                fast_rcp(ea + eb + ec + ed);
  // --- EM (SoftPool) ---
  float mx = fmaxf(fmaxf(a, b), fmaxf(c, d));
  float fa = __expf(a - mx);
  float fb = __expf(b - mx);
  float fc = __expf(c - mx);
  float fd = __expf(d - mx);
  float em = (fa * a + fb * b + fc * c + fd * d) *
             fast_rcp(fa + fb + fc + fd);
  // --- blend + nan_to_num ---
  float r = beta * edscw + (1.0f - beta) * em;
  if (isnan(r))      r = 0.0f;
  else if (isinf(r)) r = (r > 0.0f) ? FLT_MAX : -FLT_MAX;
  return r;
}

__global__ void __launch_bounds__(256)
adapool2d_kernel(const float* __restrict__ x,
                 const float* __restrict__ beta,
                 float* __restrict__ out) {
  int tid = blockIdx.x * blockDim.x + threadIdx.x;
  if (tid >= kTotalThreads) return;

  int ow2 = tid % kOW2;          // which pair of output columns
  int t   = tid / kOW2;
  int oh  = t % kOH;
  int bc  = t / kOH;             // fused batch*channel

  // Input window rows: 2*oh and 2*oh+1, columns 4*ow2 .. 4*ow2+3
  const float* rowp = x + (size_t)bc * (kH * kW)
                        + (size_t)(2 * oh) * kW
                        + 4 * ow2;
  float4 r0 = *reinterpret_cast<const float4*>(rowp);
  float4 r1 = *reinterpret_cast<const float4*>(rowp + kW);

  // beta[oh][2*ow2 .. 2*ow2+1] — 8B-aligned; L2-resident (reused over B*C)
  float2 bt = *reinterpret_cast<const float2*>(beta + oh * kOW + 2 * ow2);

  f32x2 o;
  o.x = window(r0.x, r0.y, r1.x, r1.y, bt.x);
  o.y = window(r0.z, r0.w, r1.z, r1.w, bt.y);

  // Nontemporal store: stream the 51MB output past L2 (no write-allocate
  // pollution of the read stream). Loads stay cached.
  float* outp = out + (size_t)bc * (kOH * kOW) + (size_t)oh * kOW + 2 * ow2;
  __builtin_nontemporal_store(o, reinterpret_cast<f32x2*>(outp));
}

}  // namespace

extern "C" void kernel_launch(void* const* d_in, const int* in_sizes, int n_in,
                              void* d_out, int out_size, void* d_ws, size_t ws_size,
                              hipStream_t stream) {
  const float* x    = (const float*)d_in[0];
  const float* beta = (const float*)d_in[1];
  float* out        = (float*)d_out;

  constexpr int threads = 256;
  constexpr int blocks  = (kTotalThreads + threads - 1) / threads;
  adapool2d_kernel<<<blocks, threads, 0, stream>>>(x, beta, out);
}